// Round 14
// baseline (266.805 us; speedup 1.0000x reference)
//
#include <hip/hip_runtime.h>
#include <math.h>

#define B_      16
#define NH      32
#define NKV     8
#define HD      128
#define GQ      4
#define LWIN    4096
#define BS      16
#define MAXB    385
#define HIDDEN  4096
#define QKV_COLS 6144
#define TAB_N   4100
#define T_CUR   4080      // window index of the current (new) token
#define KS      64        // k-rows per gemm split slice
#define NSPLIT  64        // number of k slices (4096/KS)
#define NCHUNK  8         // 512-token chunks
#define SCALE   0.088388347648318447f   // 128^-0.5
#define LOG1E4  9.210340371976184
#define TWO_PI  6.283185307179586
#define INV_2PI 0.15915494309189535

typedef float f4v __attribute__((ext_vector_type(4)));

// ---------------- split-K skinny QKV GEMM partial: part[ky][b][n] ----------------
// DIAGNOSTIC THIS ROUND: reps=20 idempotent re-execution of the GEMM body to
// surface this dispatch in rocprof top-5 (t_cold + 19*t_hot; W is L3-resident
// on hot reps). Table-build + zeroing hoisted out of the rep loop.
__global__ __launch_bounds__(128, 1) void k_gemm_qkv(
    const float* __restrict__ X, const float* __restrict__ W,
    float* __restrict__ part,
    float* __restrict__ ctab, float* __restrict__ stab,
    float* __restrict__ pk, float* __restrict__ pv, int reps) {
  int tid = threadIdx.x;
  int k0 = blockIdx.y * KS;
  int n4 = (blockIdx.x * 128 + tid) * 4;
  for (int rep = 0; rep < reps; rep++) {
    f4v acc[B_];
#pragma unroll
    for (int b = 0; b < B_; b++) acc[b] = (f4v){0.f, 0.f, 0.f, 0.f};
    const float* wp = W + (size_t)k0 * QKV_COLS + n4;
    const float* xp = X + k0;
#pragma unroll
    for (int batch = 0; batch < KS / 16; batch++) {
      f4v w[16];
#pragma unroll
      for (int i = 0; i < 16; i++)
        w[i] = *(const f4v*)&wp[(size_t)(batch * 16 + i) * QKV_COLS];
#pragma unroll
      for (int i = 0; i < 16; i++) {
        int kk = batch * 16 + i;
#pragma unroll
        for (int b = 0; b < B_; b++) {
          float x = xp[b * HIDDEN + kk];
          acc[b][0] = fmaf(x, w[i][0], acc[b][0]);
          acc[b][1] = fmaf(x, w[i][1], acc[b][1]);
          acc[b][2] = fmaf(x, w[i][2], acc[b][2]);
          acc[b][3] = fmaf(x, w[i][3], acc[b][3]);
        }
      }
    }
    float* pp = part + (size_t)blockIdx.y * B_ * QKV_COLS + n4;
#pragma unroll
    for (int b = 0; b < B_; b++) *(f4v*)&pp[(size_t)b * QKV_COLS] = acc[b];
  }

  // fused: trig tables + patched-block zeroing (once; 768 blocks x 128 = 98304 workers)
  int idx = (blockIdx.y * gridDim.x + blockIdx.x) * 128 + tid;
  if (idx < 64 * (TAB_N / 4)) {
    int d = idx / (TAB_N / 4);
    int q = idx - d * (TAB_N / 4);
    int i0 = q * 4;
    double f = exp(-(double)d / 64.0 * LOG1E4);
    double a = (double)(i0 - 1) * f;
    double rev = a * INV_2PI;
    rev -= rint(rev);
    float r = (float)(rev * TWO_PI);
    float c = cosf(r), s = sinf(r);
    float ff = (float)f;
    float cf = cosf(ff), sf = sinf(ff);
    int base = d * TAB_N + i0;
    ctab[base] = c; stab[base] = s;
#pragma unroll
    for (int j = 1; j < 4; j++) {
      float cn = c * cf - s * sf;
      float sn = s * cf + c * sf;
      c = cn; s = sn;
      ctab[base + j] = c; stab[base + j] = s;
    }
  }
  for (int z = idx; z < B_ * NKV * HD * BS; z += 98304) { pk[z] = 0.f; pv[z] = 0.f; }
}

// ------------- reduce qkv partials + RoPE + scatter q / patched k,v -------------
__global__ __launch_bounds__(256) void k_qkv_finish(
    const float* __restrict__ part, const int* __restrict__ positions,
    const float* __restrict__ ctab, const float* __restrict__ stab,
    float* __restrict__ qout, float* __restrict__ pk, float* __restrict__ pv) {
  int idx = blockIdx.x * 256 + threadIdx.x;
  int b = idx / 3584;
  int u = idx - b * 3584;
  if (b >= B_) return;
  if (u < 2560) {                       // rope pair units: h in [0,40), j in [0,64)
    int h = u >> 6, j = u & 63;
    int c1 = h * 128 + j;
    int c2 = c1 + 64;
    float s1 = 0.f, s2 = 0.f;
#pragma unroll 8
    for (int ky = 0; ky < NSPLIT; ky++) {
      const float* p = part + ((size_t)ky * B_ + b) * QKV_COLS;
      s1 += p[c1];
      s2 += p[c2];
    }
    int pos = min(positions[b], LWIN - 1);
    float c = ctab[j * TAB_N + pos + 1];
    float s = stab[j * TAB_N + pos + 1];
    float o1 = s1 * c - s2 * s;
    float o2 = s2 * c + s1 * s;
    if (h < NH) {
      qout[b * HIDDEN + c1] = o1;
      qout[b * HIDDEN + c2] = o2;
    } else {
      int kv = h - NH;
      pk[((b * NKV + kv) * HD + j) * BS] = o1;
      pk[((b * NKV + kv) * HD + j + 64) * BS] = o2;
    }
  } else {                              // v units
    int vi = u - 2560;
    int kv = vi >> 7, d = vi & 127;
    int col = 5120 + vi;
    float s = 0.f;
#pragma unroll 8
    for (int ky = 0; ky < NSPLIT; ky++)
      s += part[((size_t)ky * B_ + b) * QKV_COLS + col];
    pv[((b * NKV + kv) * HD + d) * BS] = s;
  }
}

// ---------------- paged attention (R10 structure: best measured) ----------------
__global__ __launch_bounds__(128, 1) void k_attn(
    const float* __restrict__ kc, const float* __restrict__ vc,
    const int* __restrict__ bt, const float* __restrict__ qbuf,
    const float* __restrict__ pk, const float* __restrict__ pv,
    const float* __restrict__ ctab, const float* __restrict__ stab,
    float* __restrict__ partial) {
  __shared__ __align__(16) float qT[HD][GQ];      // [d][g]
  __shared__ __align__(16) float p_s[512][GQ];    // chunk-local probs
  __shared__ float redm[2][GQ];
  __shared__ float redl[2][GQ];
  __shared__ const float* kbase[32];
  __shared__ const float* vbase[32];

  int bx = blockIdx.x;
  int b = bx & 15, kv = bx >> 4;
  int chunk = blockIdx.y;   // 0..7, 512 tokens each
  int tid = threadIdx.x;
  int lane = tid & 63, wave = tid >> 6;

  for (int i = tid; i < GQ * HD; i += 128) {
    int g = i >> 7, d = i & 127;
    qT[d][g] = qbuf[b * HIDDEN + (kv * GQ + g) * HD + d];
  }
  if (tid < 32) {
    int tb = chunk * 32 + tid;          // global 16-token block index
    if (tb == 255) {
      kbase[tid] = pk + (size_t)(b * NKV + kv) * (HD * BS);
      vbase[tid] = pv + (size_t)(b * NKV + kv) * (HD * BS);
    } else {
      int lg = (tb == 0) ? 0 : (129 + tb);
      size_t off = ((size_t)bt[b * MAXB + lg] * NKV + kv) * (HD * BS);
      kbase[tid] = kc + off;
      vbase[tid] = vc + off;
    }
  }
  __syncthreads();

  // ---- phase A: scores, 256 tokens per wave; d in batches of 8 (32 loads in flight) ----
  int blk_i = lane & 15, qq = lane >> 4;
  int t0 = chunk * 512 + wave * 256 + blk_i * 16 + qq * 4;
  const float* kb = kbase[wave * 16 + blk_i] + qq * 4;
  bool rot = (t0 >= 16) && (t0 < T_CUR);
  const float* ctp = ctab + t0;
  const float* stp = stab + t0;

  float sc[GQ][4];
#pragma unroll
  for (int g = 0; g < GQ; g++)
#pragma unroll
    for (int c = 0; c < 4; c++) sc[g][c] = 0.f;

#pragma unroll
  for (int batch = 0; batch < 8; batch++) {
    f4v k1[8], k2[8], cv[8], sv[8];
#pragma unroll
    for (int i = 0; i < 8; i++) {
      int d = batch * 8 + i;
      k1[i] = *(const f4v*)(kb + d * BS);
      k2[i] = *(const f4v*)(kb + (d + 64) * BS);
      cv[i] = *(const f4v*)(ctp + d * TAB_N);
      sv[i] = *(const f4v*)(stp + d * TAB_N);
    }
#pragma unroll
    for (int i = 0; i < 8; i++) {
      int d = batch * 8 + i;
      float4 q1 = *(const float4*)&qT[d][0];
      float4 q2 = *(const float4*)&qT[d + 64][0];
      float qg1[4] = {q1.x, q1.y, q1.z, q1.w};
      float qg2[4] = {q2.x, q2.y, q2.z, q2.w};
#pragma unroll
      for (int c = 0; c < 4; c++) {
        float cc = rot ? cv[i][c] : 1.f;
        float ss = rot ? sv[i][c] : 0.f;
        float r1 = k1[i][c] * cc - k2[i][c] * ss;
        float r2 = k2[i][c] * cc + k1[i][c] * ss;
#pragma unroll
        for (int g = 0; g < GQ; g++)
          sc[g][c] = fmaf(qg1[g], r1, fmaf(qg2[g], r2, sc[g][c]));
      }
    }
  }

  // scale + validity mask + per-wave max
  float mloc[GQ];
#pragma unroll
  for (int g = 0; g < GQ; g++) {
    float m = -3e38f;
#pragma unroll
    for (int c = 0; c < 4; c++) {
      float s = (t0 + c <= T_CUR) ? sc[g][c] * SCALE : -3e38f;
      sc[g][c] = s;
      m = fmaxf(m, s);
    }
#pragma unroll
    for (int off = 1; off < 64; off <<= 1) m = fmaxf(m, __shfl_xor(m, off, 64));
    mloc[g] = m;
  }
  if (lane == 0) {
#pragma unroll
    for (int g = 0; g < GQ; g++) redm[wave][g] = mloc[g];
  }
  __syncthreads();
  float mb[GQ];
#pragma unroll
  for (int g = 0; g < GQ; g++) mb[g] = fmaxf(redm[0][g], redm[1][g]);

  // probs + per-wave sums
  float4 prc[4];
  float ls[GQ] = {0.f, 0.f, 0.f, 0.f};
#pragma unroll
  for (int c = 0; c < 4; c++) {
    float p0 = __expf(sc[0][c] - mb[0]);
    float p1 = __expf(sc[1][c] - mb[1]);
    float p2 = __expf(sc[2][c] - mb[2]);
    float p3 = __expf(sc[3][c] - mb[3]);
    ls[0] += p0; ls[1] += p1; ls[2] += p2; ls[3] += p3;
    prc[c] = make_float4(p0, p1, p2, p3);
  }
#pragma unroll
  for (int g = 0; g < GQ; g++) {
    float v = ls[g];
#pragma unroll
    for (int off = 1; off < 64; off <<= 1) v += __shfl_xor(v, off, 64);
    ls[g] = v;
  }
  if (lane == 0) {
#pragma unroll
    for (int g = 0; g < GQ; g++) redl[wave][g] = ls[g];
  }
  int trow = t0 - chunk * 512;
#pragma unroll
  for (int c = 0; c < 4; c++) *(float4*)&p_s[trow + c][0] = prc[c];
  __syncthreads();   // p_s / redl complete

  // ---- phase B: PV; V-blocks in batches of 4 (16 loads in flight) ----
  float acc0 = 0.f, acc1 = 0.f, acc2 = 0.f, acc3 = 0.f;
  int d_own = tid;   // 0..127
#pragma unroll
  for (int bt4 = 0; bt4 < 8; bt4++) {
    f4v vr[4][4];
#pragma unroll
    for (int t = 0; t < 4; t++) {
      const float* vb = vbase[bt4 * 4 + t] + d_own * BS;
      vr[t][0] = *(const f4v*)(vb);
      vr[t][1] = *(const f4v*)(vb + 4);
      vr[t][2] = *(const f4v*)(vb + 8);
      vr[t][3] = *(const f4v*)(vb + 12);
    }
#pragma unroll
    for (int t = 0; t < 4; t++) {
      const float* pp = &p_s[(bt4 * 4 + t) * 16][0];
#pragma unroll
      for (int jq = 0; jq < 4; jq++) {
#pragma unroll
        for (int j = 0; j < 4; j++) {
          float4 pj = *(const float4*)(pp + (jq * 4 + j) * GQ);
          float vv = vr[t][jq][j];
          acc0 = fmaf(pj.x, vv, acc0);
          acc1 = fmaf(pj.y, vv, acc1);
          acc2 = fmaf(pj.z, vv, acc2);
          acc3 = fmaf(pj.w, vv, acc3);
        }
      }
    }
  }

  int pid = b * NKV + kv;
  float* pw = partial + ((size_t)pid * NCHUNK + chunk) * (GQ * 130);
  pw[0 * 130 + 2 + d_own] = acc0;
  pw[1 * 130 + 2 + d_own] = acc1;
  pw[2 * 130 + 2 + d_own] = acc2;
  pw[3 * 130 + 2 + d_own] = acc3;
  if (tid == 0) {
#pragma unroll
    for (int g = 0; g < GQ; g++) {
      pw[g * 130 + 0] = mb[g];
      pw[g * 130 + 1] = redl[0][g] + redl[1][g];
    }
  }
}

// ------- w_o GEMM with fused chunk-combine (X-tile built from apart in-block) -------
__global__ __launch_bounds__(128, 1) void k_gemm_o(
    const float* __restrict__ apart, const float* __restrict__ W,
    float* __restrict__ part) {
  __shared__ __align__(16) float xs[B_][KS];      // combined X tile
  __shared__ float wexp[B_][NCHUNK];
  __shared__ float lw[B_];

  int tid = threadIdx.x;
  int k0 = blockIdx.y * KS;
  int h = k0 >> 7, kv = h >> 2, g = h & 3, d0 = k0 & 127;

  // per-b flash weights (threads 0..15)
  if (tid < B_) {
    int b = tid;
    const float* pb = apart + ((size_t)(b * NKV + kv) * NCHUNK) * (GQ * 130) + g * 130;
    float M = -3e38f;
#pragma unroll
    for (int c = 0; c < NCHUNK; c++) M = fmaxf(M, pb[c * (GQ * 130)]);
    float L = 0.f;
#pragma unroll
    for (int c = 0; c < NCHUNK; c++) {
      float w = __expf(pb[c * (GQ * 130)] - M);
      wexp[b][c] = w;
      L = fmaf(pb[c * (GQ * 130) + 1], w, L);
    }
    lw[b] = L;
  }
  __syncthreads();

  // build X tile: 16 b x 64 kk, 8 items/thread
#pragma unroll
  for (int it = 0; it < 8; it++) {
    int item = it * 128 + tid;
    int b = item >> 6, kk = item & 63;
    const float* pb = apart + ((size_t)(b * NKV + kv) * NCHUNK) * (GQ * 130) + g * 130 + 2 + d0 + kk;
    float val = 0.f;
#pragma unroll
    for (int c = 0; c < NCHUNK; c++) val = fmaf(pb[c * (GQ * 130)], wexp[b][c], val);
    xs[b][kk] = val / lw[b];
  }
  __syncthreads();

  int n4 = (blockIdx.x * 128 + tid) * 4;
  f4v acc[B_];
#pragma unroll
  for (int b = 0; b < B_; b++) acc[b] = (f4v){0.f, 0.f, 0.f, 0.f};
  const float* wp = W + (size_t)k0 * HIDDEN + n4;
#pragma unroll
  for (int batch = 0; batch < KS / 16; batch++) {
    f4v w[16];
#pragma unroll
    for (int i = 0; i < 16; i++)
      w[i] = *(const f4v*)&wp[(size_t)(batch * 16 + i) * HIDDEN];
#pragma unroll
    for (int i = 0; i < 16; i++) {
      int kk = batch * 16 + i;
#pragma unroll
      for (int b = 0; b < B_; b++) {
        float x = xs[b][kk];
        acc[b][0] = fmaf(x, w[i][0], acc[b][0]);
        acc[b][1] = fmaf(x, w[i][1], acc[b][1]);
        acc[b][2] = fmaf(x, w[i][2], acc[b][2]);
        acc[b][3] = fmaf(x, w[i][3], acc[b][3]);
      }
    }
  }
  float* pp = part + (size_t)blockIdx.y * B_ * HIDDEN + n4;
#pragma unroll
  for (int b = 0; b < B_; b++) *(f4v*)&pp[(size_t)b * HIDDEN] = acc[b];
}

// ---------------- reduce w_o partials -> out ----------------
__global__ __launch_bounds__(256) void k_reduce_out(
    const float* __restrict__ part, float* __restrict__ out) {
  int idx = blockIdx.x * 256 + threadIdx.x;
  int b = idx >> 12, n = idx & 4095;
  float s = 0.f;
#pragma unroll 8
  for (int ky = 0; ky < NSPLIT; ky++)
    s += part[((size_t)ky * B_ + b) * HIDDEN + n];
  out[idx] = s;
}

extern "C" void kernel_launch(void* const* d_in, const int* in_sizes, int n_in,
                              void* d_out, int out_size, void* d_ws, size_t ws_size,
                              hipStream_t stream) {
  const int*   positions = (const int*)d_in[0];
  const float* hs        = (const float*)d_in[1];
  const float* kc        = (const float*)d_in[2];
  const float* vc        = (const float*)d_in[3];
  const int*   bt        = (const int*)d_in[4];
  const float* w_qkv     = (const float*)d_in[6];
  const float* w_o       = (const float*)d_in[7];
  float* out = (float*)d_out;

  float* ws    = (float*)d_ws;
  float* ctab  = ws;                    // 262400
  float* stab  = ctab + 262400;         // 262400
  float* pk    = stab + 262400;         // 262144
  float* pv    = pk + 262144;           // 262144
  float* qbuf  = pv + 262144;           // 65536
  float* apart = qbuf + 65536;          // 128*8*4*130 = 532480
  float* gpart = apart + 532480;        // 64*16*6144 = 6291456

  // DIAGNOSTIC: reps=20 on the QKV GEMM (idempotent) to surface it in top-5.
  k_gemm_qkv<<<dim3(QKV_COLS / 512, NSPLIT), 128, 0, stream>>>(
      hs, w_qkv, gpart, ctab, stab, pk, pv, 20);
  k_qkv_finish<<<(B_ * 3584) / 256, 256, 0, stream>>>(gpart, positions, ctab, stab, qbuf, pk, pv);
  k_attn<<<dim3(B_ * NKV, NCHUNK), 128, 0, stream>>>(kc, vc, bt, qbuf, pk, pv, ctab, stab, apart);
  k_gemm_o<<<dim3(HIDDEN / 512, NSPLIT), 128, 0, stream>>>(apart, w_o, gpart);
  k_reduce_out<<<(B_ * HIDDEN) / 256, 256, 0, stream>>>(gpart, out);
}

// Round 15
// 214.426 us; speedup vs baseline: 1.2443x; 1.2443x over previous
//
#include <hip/hip_runtime.h>
#include <math.h>

#define B_      16
#define NH      32
#define NKV     8
#define HD      128
#define GQ      4
#define LWIN    4096
#define BS      16
#define MAXB    385
#define HIDDEN  4096
#define QKV_COLS 6144
#define TAB_N   4100
#define T_CUR   4080      // window index of the current (new) token
#define KS      64        // k-rows per gemm split slice
#define NSPLIT  64        // number of k slices (4096/KS)
#define NCHUNK  8         // 512-token chunks
#define KSTR    2064      // kst block stride (floats): %32==16 -> 2-way max (free)
#define SCALE   0.088388347648318447f   // 128^-0.5
#define LOG1E4  9.210340371976184
#define TWO_PI  6.283185307179586
#define INV_2PI 0.15915494309189535

typedef float f4v __attribute__((ext_vector_type(4)));

// ---------------- split-K skinny QKV GEMM partial: part[ky][b][n] ----------------
__global__ __launch_bounds__(128, 1) void k_gemm_qkv(
    const float* __restrict__ X, const float* __restrict__ W,
    float* __restrict__ part,
    float* __restrict__ ctab, float* __restrict__ stab,
    float* __restrict__ pk, float* __restrict__ pv) {
  int tid = threadIdx.x;
  int k0 = blockIdx.y * KS;
  int n4 = (blockIdx.x * 128 + tid) * 4;
  f4v acc[B_];
#pragma unroll
  for (int b = 0; b < B_; b++) acc[b] = (f4v){0.f, 0.f, 0.f, 0.f};
  const float* wp = W + (size_t)k0 * QKV_COLS + n4;
  const float* xp = X + k0;
#pragma unroll
  for (int batch = 0; batch < KS / 16; batch++) {
    f4v w[16];
#pragma unroll
    for (int i = 0; i < 16; i++)
      w[i] = *(const f4v*)&wp[(size_t)(batch * 16 + i) * QKV_COLS];
#pragma unroll
    for (int i = 0; i < 16; i++) {
      int kk = batch * 16 + i;
#pragma unroll
      for (int b = 0; b < B_; b++) {
        float x = xp[b * HIDDEN + kk];
        acc[b][0] = fmaf(x, w[i][0], acc[b][0]);
        acc[b][1] = fmaf(x, w[i][1], acc[b][1]);
        acc[b][2] = fmaf(x, w[i][2], acc[b][2]);
        acc[b][3] = fmaf(x, w[i][3], acc[b][3]);
      }
    }
  }
  float* pp = part + (size_t)blockIdx.y * B_ * QKV_COLS + n4;
#pragma unroll
  for (int b = 0; b < B_; b++) *(f4v*)&pp[(size_t)b * QKV_COLS] = acc[b];

  // fused: trig tables + patched-block zeroing (768 blocks x 128 = 98304 workers)
  int idx = (blockIdx.y * gridDim.x + blockIdx.x) * 128 + tid;
  if (idx < 64 * (TAB_N / 4)) {
    int d = idx / (TAB_N / 4);
    int q = idx - d * (TAB_N / 4);
    int i0 = q * 4;
    double f = exp(-(double)d / 64.0 * LOG1E4);
    double a = (double)(i0 - 1) * f;
    double rev = a * INV_2PI;
    rev -= rint(rev);
    float r = (float)(rev * TWO_PI);
    float c = cosf(r), s = sinf(r);
    float ff = (float)f;
    float cf = cosf(ff), sf = sinf(ff);
    int base = d * TAB_N + i0;
    ctab[base] = c; stab[base] = s;
#pragma unroll
    for (int j = 1; j < 4; j++) {
      float cn = c * cf - s * sf;
      float sn = s * cf + c * sf;
      c = cn; s = sn;
      ctab[base + j] = c; stab[base + j] = s;
    }
  }
  for (int z = idx; z < B_ * NKV * HD * BS; z += 98304) { pk[z] = 0.f; pv[z] = 0.f; }
}

// ------------- reduce qkv partials + RoPE + scatter q / patched k,v -------------
__global__ __launch_bounds__(256) void k_qkv_finish(
    const float* __restrict__ part, const int* __restrict__ positions,
    const float* __restrict__ ctab, const float* __restrict__ stab,
    float* __restrict__ qout, float* __restrict__ pk, float* __restrict__ pv) {
  int idx = blockIdx.x * 256 + threadIdx.x;
  int b = idx / 3584;
  int u = idx - b * 3584;
  if (b >= B_) return;
  if (u < 2560) {                       // rope pair units: h in [0,40), j in [0,64)
    int h = u >> 6, j = u & 63;
    int c1 = h * 128 + j;
    int c2 = c1 + 64;
    float s1 = 0.f, s2 = 0.f;
#pragma unroll 8
    for (int ky = 0; ky < NSPLIT; ky++) {
      const float* p = part + ((size_t)ky * B_ + b) * QKV_COLS;
      s1 += p[c1];
      s2 += p[c2];
    }
    int pos = min(positions[b], LWIN - 1);
    float c = ctab[j * TAB_N + pos + 1];
    float s = stab[j * TAB_N + pos + 1];
    float o1 = s1 * c - s2 * s;
    float o2 = s2 * c + s1 * s;
    if (h < NH) {
      qout[b * HIDDEN + c1] = o1;
      qout[b * HIDDEN + c2] = o2;
    } else {
      int kv = h - NH;
      pk[((b * NKV + kv) * HD + j) * BS] = o1;
      pk[((b * NKV + kv) * HD + j + 64) * BS] = o2;
    }
  } else {                              // v units
    int vi = u - 2560;
    int kv = vi >> 7, d = vi & 127;
    int col = 5120 + vi;
    float s = 0.f;
#pragma unroll 8
    for (int ky = 0; ky < NSPLIT; ky++)
      s += part[((size_t)ky * B_ + b) * QKV_COLS + col];
    pv[((b * NKV + kv) * HD + d) * BS] = s;
  }
}

// ------- paged attention: LDS-staged K (T14 async-STAGE), double-buffered -------
// Phase A: 16 iters x 2 K-blocks. Loads for iter+1 issued to regs BEFORE the
// compute of iter (stay in flight across barriers); vmcnt+ds_write after.
// Per wave only 2 concurrent DRAM streams with dense 8KB runs (was 16).
__global__ __launch_bounds__(128, 1) void k_attn(
    const float* __restrict__ kc, const float* __restrict__ vc,
    const int* __restrict__ bt, const float* __restrict__ qbuf,
    const float* __restrict__ pk, const float* __restrict__ pv,
    const float* __restrict__ ctab, const float* __restrict__ stab,
    float* __restrict__ partial) {
  __shared__ __align__(16) float kst[2][2][KSTR];  // 66 KB staged K
  __shared__ __align__(16) float qT[HD][GQ];       // [d][g]
  __shared__ __align__(16) float p_s[512][GQ];     // raw scores -> probs
  __shared__ __align__(16) float sps[32][GQ];      // cross-wave partial scores
  __shared__ float redm[2][GQ];
  __shared__ float redl[2][GQ];
  __shared__ const float* kbase[32];
  __shared__ const float* vbase[32];

  int bx = blockIdx.x;
  int b = bx & 15, kv = bx >> 4;
  int chunk = blockIdx.y;   // 0..7, 512 tokens each
  int tid = threadIdx.x;
  int lane = tid & 63, wave = tid >> 6;

  for (int i = tid; i < GQ * HD; i += 128) {
    int g = i >> 7, d = i & 127;
    qT[d][g] = qbuf[b * HIDDEN + (kv * GQ + g) * HD + d];
  }
  if (tid < 32) {
    int tb = chunk * 32 + tid;          // global 16-token block index
    if (tb == 255) {
      kbase[tid] = pk + (size_t)(b * NKV + kv) * (HD * BS);
      vbase[tid] = pv + (size_t)(b * NKV + kv) * (HD * BS);
    } else {
      int lg = (tb == 0) ? 0 : (129 + tb);
      size_t off = ((size_t)bt[b * MAXB + lg] * NKV + kv) * (HD * BS);
      kbase[tid] = kc + off;
      vbase[tid] = vc + off;
    }
  }
  __syncthreads();

  // ---- phase A ----
  int t32 = tid & 31;                   // token within 2-block group
  int dq  = tid >> 5;                   // 0..3: rotation-pair quarter
  f4v st0[4], st1[4];

  // prologue: stage group 0
  {
    const float* kb0 = kbase[0];
    const float* kb1 = kbase[1];
#pragma unroll
    for (int i = 0; i < 4; i++) st0[i] = *(const f4v*)(kb0 + tid * 16 + i * 4);
#pragma unroll
    for (int i = 0; i < 4; i++) st1[i] = *(const f4v*)(kb1 + tid * 16 + i * 4);
#pragma unroll
    for (int i = 0; i < 4; i++) *(f4v*)&kst[0][0][tid * 16 + i * 4] = st0[i];
#pragma unroll
    for (int i = 0; i < 4; i++) *(f4v*)&kst[0][1][tid * 16 + i * 4] = st1[i];
  }
  __syncthreads();

  for (int it = 0; it < 16; it++) {
    int cur = it & 1;
    // issue next group's loads (regs; no wait)
    if (it < 15) {
      const float* kb0 = kbase[(it + 1) * 2];
      const float* kb1 = kbase[(it + 1) * 2 + 1];
#pragma unroll
      for (int i = 0; i < 4; i++) st0[i] = *(const f4v*)(kb0 + tid * 16 + i * 4);
#pragma unroll
      for (int i = 0; i < 4; i++) st1[i] = *(const f4v*)(kb1 + tid * 16 + i * 4);
    }
    // compute from kst[cur]: token t32, rotation pairs d in [dq*16, dq*16+16)
    int tg = chunk * 512 + it * 32 + t32;
    bool rot = (tg >= 16) && (tg < T_CUR);
    int blk = t32 >> 4, tt = t32 & 15;
    const float* kcl = &kst[cur][blk][0];
    float sc0 = 0.f, sc1 = 0.f, sc2 = 0.f, sc3 = 0.f;
#pragma unroll
    for (int i = 0; i < 16; i++) {
      int d = dq * 16 + i;
      float k1 = kcl[d * 16 + tt];
      float k2 = kcl[(d + 64) * 16 + tt];
      float cc = rot ? ctab[d * TAB_N + tg] : 1.f;
      float ss = rot ? stab[d * TAB_N + tg] : 0.f;
      float r1 = k1 * cc - k2 * ss;
      float r2 = k2 * cc + k1 * ss;
      float4 q1 = *(const float4*)&qT[d][0];
      float4 q2 = *(const float4*)&qT[d + 64][0];
      sc0 = fmaf(q1.x, r1, fmaf(q2.x, r2, sc0));
      sc1 = fmaf(q1.y, r1, fmaf(q2.y, r2, sc1));
      sc2 = fmaf(q1.z, r1, fmaf(q2.z, r2, sc2));
      sc3 = fmaf(q1.w, r1, fmaf(q2.w, r2, sc3));
    }
    // merge dq pairs within wave (tid bit5 == lane bit5)
    sc0 += __shfl_xor(sc0, 32, 64);
    sc1 += __shfl_xor(sc1, 32, 64);
    sc2 += __shfl_xor(sc2, 32, 64);
    sc3 += __shfl_xor(sc3, 32, 64);
    // wave1 lanes<32 hold the (dq2+dq3) half
    if (wave == 1 && lane < 32)
      *(float4*)&sps[lane][0] = make_float4(sc0, sc1, sc2, sc3);
    __syncthreads();
    if (wave == 0 && lane < 32) {
      float4 o = *(const float4*)&sps[lane][0];
      *(float4*)&p_s[it * 32 + lane][0] =
          make_float4(sc0 + o.x, sc1 + o.y, sc2 + o.z, sc3 + o.w);
    }
    // write staged regs -> other buffer (vmcnt waits here, after overlap)
    if (it < 15) {
      int nxt = cur ^ 1;
#pragma unroll
      for (int i = 0; i < 4; i++) *(f4v*)&kst[nxt][0][tid * 16 + i * 4] = st0[i];
#pragma unroll
      for (int i = 0; i < 4; i++) *(f4v*)&kst[nxt][1][tid * 16 + i * 4] = st1[i];
    }
    __syncthreads();
  }

  // ---- softmax over the 512-token chunk (R11-proven LDS roundtrip) ----
  int blk_i = lane & 15, qq = lane >> 4;
  int trow = wave * 256 + blk_i * 16 + qq * 4;
  int t0 = chunk * 512 + trow;
  float sc[GQ][4];
#pragma unroll
  for (int c = 0; c < 4; c++) {
    float4 r = *(const float4*)&p_s[trow + c][0];
    sc[0][c] = r.x; sc[1][c] = r.y; sc[2][c] = r.z; sc[3][c] = r.w;
  }
  float mloc[GQ];
#pragma unroll
  for (int g = 0; g < GQ; g++) {
    float m = -3e38f;
#pragma unroll
    for (int c = 0; c < 4; c++) {
      float s = (t0 + c <= T_CUR) ? sc[g][c] * SCALE : -3e38f;
      sc[g][c] = s;
      m = fmaxf(m, s);
    }
#pragma unroll
    for (int off = 1; off < 64; off <<= 1) m = fmaxf(m, __shfl_xor(m, off, 64));
    mloc[g] = m;
  }
  if (lane == 0) {
#pragma unroll
    for (int g = 0; g < GQ; g++) redm[wave][g] = mloc[g];
  }
  __syncthreads();
  float mb[GQ];
#pragma unroll
  for (int g = 0; g < GQ; g++) mb[g] = fmaxf(redm[0][g], redm[1][g]);

  float4 prc[4];
  float ls[GQ] = {0.f, 0.f, 0.f, 0.f};
#pragma unroll
  for (int c = 0; c < 4; c++) {
    float p0 = __expf(sc[0][c] - mb[0]);
    float p1 = __expf(sc[1][c] - mb[1]);
    float p2 = __expf(sc[2][c] - mb[2]);
    float p3 = __expf(sc[3][c] - mb[3]);
    ls[0] += p0; ls[1] += p1; ls[2] += p2; ls[3] += p3;
    prc[c] = make_float4(p0, p1, p2, p3);
  }
#pragma unroll
  for (int g = 0; g < GQ; g++) {
    float v = ls[g];
#pragma unroll
    for (int off = 1; off < 64; off <<= 1) v += __shfl_xor(v, off, 64);
    ls[g] = v;
  }
  if (lane == 0) {
#pragma unroll
    for (int g = 0; g < GQ; g++) redl[wave][g] = ls[g];
  }
#pragma unroll
  for (int c = 0; c < 4; c++) *(float4*)&p_s[trow + c][0] = prc[c];
  __syncthreads();   // probs / redl complete

  // ---- phase B: PV; V-blocks in batches of 4 (16 loads in flight) ----
  float acc0 = 0.f, acc1 = 0.f, acc2 = 0.f, acc3 = 0.f;
  int d_own = tid;   // 0..127
#pragma unroll
  for (int bt4 = 0; bt4 < 8; bt4++) {
    f4v vr[4][4];
#pragma unroll
    for (int t = 0; t < 4; t++) {
      const float* vb = vbase[bt4 * 4 + t] + d_own * BS;
      vr[t][0] = *(const f4v*)(vb);
      vr[t][1] = *(const f4v*)(vb + 4);
      vr[t][2] = *(const f4v*)(vb + 8);
      vr[t][3] = *(const f4v*)(vb + 12);
    }
#pragma unroll
    for (int t = 0; t < 4; t++) {
      const float* pp = &p_s[(bt4 * 4 + t) * 16][0];
#pragma unroll
      for (int jq = 0; jq < 4; jq++) {
#pragma unroll
        for (int j = 0; j < 4; j++) {
          float4 pj = *(const float4*)(pp + (jq * 4 + j) * GQ);
          float vv = vr[t][jq][j];
          acc0 = fmaf(pj.x, vv, acc0);
          acc1 = fmaf(pj.y, vv, acc1);
          acc2 = fmaf(pj.z, vv, acc2);
          acc3 = fmaf(pj.w, vv, acc3);
        }
      }
    }
  }

  int pid = b * NKV + kv;
  float* pw = partial + ((size_t)pid * NCHUNK + chunk) * (GQ * 130);
  pw[0 * 130 + 2 + d_own] = acc0;
  pw[1 * 130 + 2 + d_own] = acc1;
  pw[2 * 130 + 2 + d_own] = acc2;
  pw[3 * 130 + 2 + d_own] = acc3;
  if (tid == 0) {
#pragma unroll
    for (int g = 0; g < GQ; g++) {
      pw[g * 130 + 0] = mb[g];
      pw[g * 130 + 1] = redl[0][g] + redl[1][g];
    }
  }
}

// ------- w_o GEMM with fused chunk-combine (X-tile built from apart in-block) -------
__global__ __launch_bounds__(128, 1) void k_gemm_o(
    const float* __restrict__ apart, const float* __restrict__ W,
    float* __restrict__ part) {
  __shared__ __align__(16) float xs[B_][KS];      // combined X tile
  __shared__ float wexp[B_][NCHUNK];
  __shared__ float lw[B_];

  int tid = threadIdx.x;
  int k0 = blockIdx.y * KS;
  int h = k0 >> 7, kv = h >> 2, g = h & 3, d0 = k0 & 127;

  if (tid < B_) {
    int b = tid;
    const float* pb = apart + ((size_t)(b * NKV + kv) * NCHUNK) * (GQ * 130) + g * 130;
    float M = -3e38f;
#pragma unroll
    for (int c = 0; c < NCHUNK; c++) M = fmaxf(M, pb[c * (GQ * 130)]);
    float L = 0.f;
#pragma unroll
    for (int c = 0; c < NCHUNK; c++) {
      float w = __expf(pb[c * (GQ * 130)] - M);
      wexp[b][c] = w;
      L = fmaf(pb[c * (GQ * 130) + 1], w, L);
    }
    lw[b] = L;
  }
  __syncthreads();

#pragma unroll
  for (int it = 0; it < 8; it++) {
    int item = it * 128 + tid;
    int b = item >> 6, kk = item & 63;
    const float* pb = apart + ((size_t)(b * NKV + kv) * NCHUNK) * (GQ * 130) + g * 130 + 2 + d0 + kk;
    float val = 0.f;
#pragma unroll
    for (int c = 0; c < NCHUNK; c++) val = fmaf(pb[c * (GQ * 130)], wexp[b][c], val);
    xs[b][kk] = val / lw[b];
  }
  __syncthreads();

  int n4 = (blockIdx.x * 128 + tid) * 4;
  f4v acc[B_];
#pragma unroll
  for (int b = 0; b < B_; b++) acc[b] = (f4v){0.f, 0.f, 0.f, 0.f};
  const float* wp = W + (size_t)k0 * HIDDEN + n4;
#pragma unroll
  for (int batch = 0; batch < KS / 16; batch++) {
    f4v w[16];
#pragma unroll
    for (int i = 0; i < 16; i++)
      w[i] = *(const f4v*)&wp[(size_t)(batch * 16 + i) * HIDDEN];
#pragma unroll
    for (int i = 0; i < 16; i++) {
      int kk = batch * 16 + i;
#pragma unroll
      for (int b = 0; b < B_; b++) {
        float x = xs[b][kk];
        acc[b][0] = fmaf(x, w[i][0], acc[b][0]);
        acc[b][1] = fmaf(x, w[i][1], acc[b][1]);
        acc[b][2] = fmaf(x, w[i][2], acc[b][2]);
        acc[b][3] = fmaf(x, w[i][3], acc[b][3]);
      }
    }
  }
  float* pp = part + (size_t)blockIdx.y * B_ * HIDDEN + n4;
#pragma unroll
  for (int b = 0; b < B_; b++) *(f4v*)&pp[(size_t)b * HIDDEN] = acc[b];
}

// ---------------- reduce w_o partials -> out ----------------
__global__ __launch_bounds__(256) void k_reduce_out(
    const float* __restrict__ part, float* __restrict__ out) {
  int idx = blockIdx.x * 256 + threadIdx.x;
  int b = idx >> 12, n = idx & 4095;
  float s = 0.f;
#pragma unroll 8
  for (int ky = 0; ky < NSPLIT; ky++)
    s += part[((size_t)ky * B_ + b) * HIDDEN + n];
  out[idx] = s;
}

extern "C" void kernel_launch(void* const* d_in, const int* in_sizes, int n_in,
                              void* d_out, int out_size, void* d_ws, size_t ws_size,
                              hipStream_t stream) {
  const int*   positions = (const int*)d_in[0];
  const float* hs        = (const float*)d_in[1];
  const float* kc        = (const float*)d_in[2];
  const float* vc        = (const float*)d_in[3];
  const int*   bt        = (const int*)d_in[4];
  const float* w_qkv     = (const float*)d_in[6];
  const float* w_o       = (const float*)d_in[7];
  float* out = (float*)d_out;

  float* ws    = (float*)d_ws;
  float* ctab  = ws;                    // 262400
  float* stab  = ctab + 262400;         // 262400
  float* pk    = stab + 262400;         // 262144
  float* pv    = pk + 262144;           // 262144
  float* qbuf  = pv + 262144;           // 65536
  float* apart = qbuf + 65536;          // 128*8*4*130 = 532480
  float* gpart = apart + 532480;        // 64*16*6144 = 6291456

  k_gemm_qkv<<<dim3(QKV_COLS / 512, NSPLIT), 128, 0, stream>>>(
      hs, w_qkv, gpart, ctab, stab, pk, pv);
  k_qkv_finish<<<(B_ * 3584) / 256, 256, 0, stream>>>(gpart, positions, ctab, stab, qbuf, pk, pv);
  k_attn<<<dim3(B_ * NKV, NCHUNK), 128, 0, stream>>>(kc, vc, bt, qbuf, pk, pv, ctab, stab, apart);
  k_gemm_o<<<dim3(HIDDEN / 512, NSPLIT), 128, 0, stream>>>(apart, w_o, gpart);
  k_reduce_out<<<(B_ * HIDDEN) / 256, 256, 0, stream>>>(gpart, out);
}

// Round 16
// 208.413 us; speedup vs baseline: 1.2802x; 1.0288x over previous
//
#include <hip/hip_runtime.h>
#include <math.h>

#define B_      16
#define NH      32
#define NKV     8
#define HD      128
#define GQ      4
#define LWIN    4096
#define BS      16
#define MAXB    385
#define HIDDEN  4096
#define QKV_COLS 6144
#define TAB_N   4100
#define T_CUR   4080      // window index of the current (new) token
#define KS      64        // k-rows per gemm split slice
#define NSPLIT  64        // number of k slices (4096/KS)
#define NCHUNK  8         // 512-token chunks
#define SCALE   0.088388347648318447f   // 128^-0.5
#define LOG1E4  9.210340371976184
#define TWO_PI  6.283185307179586
#define INV_2PI 0.15915494309189535

typedef float f4v __attribute__((ext_vector_type(4)));

// ---------------- split-K skinny QKV GEMM partial: part[ky][b][n] ----------------
// Deep pipeline: 16 W-row loads (64 VGPR) in flight. Afterwards: build trig
// tables + zero patched k/v blocks (fp64 rides free under the W stream).
__global__ __launch_bounds__(128, 1) void k_gemm_qkv(
    const float* __restrict__ X, const float* __restrict__ W,
    float* __restrict__ part,
    float* __restrict__ ctab, float* __restrict__ stab,
    float* __restrict__ pk, float* __restrict__ pv) {
  int tid = threadIdx.x;
  int k0 = blockIdx.y * KS;
  int n4 = (blockIdx.x * 128 + tid) * 4;
  f4v acc[B_];
#pragma unroll
  for (int b = 0; b < B_; b++) acc[b] = (f4v){0.f, 0.f, 0.f, 0.f};
  const float* wp = W + (size_t)k0 * QKV_COLS + n4;
  const float* xp = X + k0;
#pragma unroll
  for (int batch = 0; batch < KS / 16; batch++) {
    f4v w[16];
#pragma unroll
    for (int i = 0; i < 16; i++)
      w[i] = *(const f4v*)&wp[(size_t)(batch * 16 + i) * QKV_COLS];
#pragma unroll
    for (int i = 0; i < 16; i++) {
      int kk = batch * 16 + i;
#pragma unroll
      for (int b = 0; b < B_; b++) {
        float x = xp[b * HIDDEN + kk];
        acc[b][0] = fmaf(x, w[i][0], acc[b][0]);
        acc[b][1] = fmaf(x, w[i][1], acc[b][1]);
        acc[b][2] = fmaf(x, w[i][2], acc[b][2]);
        acc[b][3] = fmaf(x, w[i][3], acc[b][3]);
      }
    }
  }
  float* pp = part + (size_t)blockIdx.y * B_ * QKV_COLS + n4;
#pragma unroll
  for (int b = 0; b < B_; b++) *(f4v*)&pp[(size_t)b * QKV_COLS] = acc[b];

  // fused: trig tables + patched-block zeroing (768 blocks x 128 = 98304 workers)
  int idx = (blockIdx.y * gridDim.x + blockIdx.x) * 128 + tid;
  if (idx < 64 * (TAB_N / 4)) {
    int d = idx / (TAB_N / 4);
    int q = idx - d * (TAB_N / 4);
    int i0 = q * 4;
    double f = exp(-(double)d / 64.0 * LOG1E4);
    double a = (double)(i0 - 1) * f;
    double rev = a * INV_2PI;
    rev -= rint(rev);
    float r = (float)(rev * TWO_PI);
    float c = cosf(r), s = sinf(r);
    float ff = (float)f;
    float cf = cosf(ff), sf = sinf(ff);
    int base = d * TAB_N + i0;
    ctab[base] = c; stab[base] = s;
#pragma unroll
    for (int j = 1; j < 4; j++) {
      float cn = c * cf - s * sf;
      float sn = s * cf + c * sf;
      c = cn; s = sn;
      ctab[base + j] = c; stab[base + j] = s;
    }
  }
  for (int z = idx; z < B_ * NKV * HD * BS; z += 98304) { pk[z] = 0.f; pv[z] = 0.f; }
}

// ------------- reduce qkv partials + RoPE + scatter q / patched k,v -------------
__global__ __launch_bounds__(256) void k_qkv_finish(
    const float* __restrict__ part, const int* __restrict__ positions,
    const float* __restrict__ ctab, const float* __restrict__ stab,
    float* __restrict__ qout, float* __restrict__ pk, float* __restrict__ pv) {
  int idx = blockIdx.x * 256 + threadIdx.x;
  int b = idx / 3584;
  int u = idx - b * 3584;
  if (b >= B_) return;
  if (u < 2560) {                       // rope pair units: h in [0,40), j in [0,64)
    int h = u >> 6, j = u & 63;
    int c1 = h * 128 + j;
    int c2 = c1 + 64;
    float s1 = 0.f, s2 = 0.f;
#pragma unroll 8
    for (int ky = 0; ky < NSPLIT; ky++) {
      const float* p = part + ((size_t)ky * B_ + b) * QKV_COLS;
      s1 += p[c1];
      s2 += p[c2];
    }
    int pos = min(positions[b], LWIN - 1);
    float c = ctab[j * TAB_N + pos + 1];
    float s = stab[j * TAB_N + pos + 1];
    float o1 = s1 * c - s2 * s;
    float o2 = s2 * c + s1 * s;
    if (h < NH) {
      qout[b * HIDDEN + c1] = o1;
      qout[b * HIDDEN + c2] = o2;
    } else {
      int kv = h - NH;
      pk[((b * NKV + kv) * HD + j) * BS] = o1;
      pk[((b * NKV + kv) * HD + j + 64) * BS] = o2;
    }
  } else {                              // v units
    int vi = u - 2560;
    int kv = vi >> 7, d = vi & 127;
    int col = 5120 + vi;
    float s = 0.f;
#pragma unroll 8
    for (int ky = 0; ky < NSPLIT; ky++)
      s += part[((size_t)ky * B_ + b) * QKV_COLS + col];
    pv[((b * NKV + kv) * HD + d) * BS] = s;
  }
}

// ---------------- paged attention (R10 structure: best measured) ----------------
__global__ __launch_bounds__(128, 1) void k_attn(
    const float* __restrict__ kc, const float* __restrict__ vc,
    const int* __restrict__ bt, const float* __restrict__ qbuf,
    const float* __restrict__ pk, const float* __restrict__ pv,
    const float* __restrict__ ctab, const float* __restrict__ stab,
    float* __restrict__ partial) {
  __shared__ __align__(16) float qT[HD][GQ];      // [d][g]
  __shared__ __align__(16) float p_s[512][GQ];    // chunk-local probs
  __shared__ float redm[2][GQ];
  __shared__ float redl[2][GQ];
  __shared__ const float* kbase[32];
  __shared__ const float* vbase[32];

  int bx = blockIdx.x;
  int b = bx & 15, kv = bx >> 4;
  int chunk = blockIdx.y;   // 0..7, 512 tokens each
  int tid = threadIdx.x;
  int lane = tid & 63, wave = tid >> 6;

  for (int i = tid; i < GQ * HD; i += 128) {
    int g = i >> 7, d = i & 127;
    qT[d][g] = qbuf[b * HIDDEN + (kv * GQ + g) * HD + d];
  }
  if (tid < 32) {
    int tb = chunk * 32 + tid;          // global 16-token block index
    if (tb == 255) {
      kbase[tid] = pk + (size_t)(b * NKV + kv) * (HD * BS);
      vbase[tid] = pv + (size_t)(b * NKV + kv) * (HD * BS);
    } else {
      int lg = (tb == 0) ? 0 : (129 + tb);
      size_t off = ((size_t)bt[b * MAXB + lg] * NKV + kv) * (HD * BS);
      kbase[tid] = kc + off;
      vbase[tid] = vc + off;
    }
  }
  __syncthreads();

  // ---- phase A: scores, 256 tokens per wave; d in batches of 8 (32 loads in flight) ----
  int blk_i = lane & 15, qq = lane >> 4;
  int t0 = chunk * 512 + wave * 256 + blk_i * 16 + qq * 4;
  const float* kb = kbase[wave * 16 + blk_i] + qq * 4;
  bool rot = (t0 >= 16) && (t0 < T_CUR);
  const float* ctp = ctab + t0;
  const float* stp = stab + t0;

  float sc[GQ][4];
#pragma unroll
  for (int g = 0; g < GQ; g++)
#pragma unroll
    for (int c = 0; c < 4; c++) sc[g][c] = 0.f;

#pragma unroll
  for (int batch = 0; batch < 8; batch++) {
    f4v k1[8], k2[8], cv[8], sv[8];
#pragma unroll
    for (int i = 0; i < 8; i++) {
      int d = batch * 8 + i;
      k1[i] = *(const f4v*)(kb + d * BS);
      k2[i] = *(const f4v*)(kb + (d + 64) * BS);
      cv[i] = *(const f4v*)(ctp + d * TAB_N);
      sv[i] = *(const f4v*)(stp + d * TAB_N);
    }
#pragma unroll
    for (int i = 0; i < 8; i++) {
      int d = batch * 8 + i;
      float4 q1 = *(const float4*)&qT[d][0];
      float4 q2 = *(const float4*)&qT[d + 64][0];
      float qg1[4] = {q1.x, q1.y, q1.z, q1.w};
      float qg2[4] = {q2.x, q2.y, q2.z, q2.w};
#pragma unroll
      for (int c = 0; c < 4; c++) {
        float cc = rot ? cv[i][c] : 1.f;
        float ss = rot ? sv[i][c] : 0.f;
        float r1 = k1[i][c] * cc - k2[i][c] * ss;
        float r2 = k2[i][c] * cc + k1[i][c] * ss;
#pragma unroll
        for (int g = 0; g < GQ; g++)
          sc[g][c] = fmaf(qg1[g], r1, fmaf(qg2[g], r2, sc[g][c]));
      }
    }
  }

  // scale + validity mask + per-wave max
  float mloc[GQ];
#pragma unroll
  for (int g = 0; g < GQ; g++) {
    float m = -3e38f;
#pragma unroll
    for (int c = 0; c < 4; c++) {
      float s = (t0 + c <= T_CUR) ? sc[g][c] * SCALE : -3e38f;
      sc[g][c] = s;
      m = fmaxf(m, s);
    }
#pragma unroll
    for (int off = 1; off < 64; off <<= 1) m = fmaxf(m, __shfl_xor(m, off, 64));
    mloc[g] = m;
  }
  if (lane == 0) {
#pragma unroll
    for (int g = 0; g < GQ; g++) redm[wave][g] = mloc[g];
  }
  __syncthreads();
  float mb[GQ];
#pragma unroll
  for (int g = 0; g < GQ; g++) mb[g] = fmaxf(redm[0][g], redm[1][g]);

  // probs + per-wave sums
  float4 prc[4];
  float ls[GQ] = {0.f, 0.f, 0.f, 0.f};
#pragma unroll
  for (int c = 0; c < 4; c++) {
    float p0 = __expf(sc[0][c] - mb[0]);
    float p1 = __expf(sc[1][c] - mb[1]);
    float p2 = __expf(sc[2][c] - mb[2]);
    float p3 = __expf(sc[3][c] - mb[3]);
    ls[0] += p0; ls[1] += p1; ls[2] += p2; ls[3] += p3;
    prc[c] = make_float4(p0, p1, p2, p3);
  }
#pragma unroll
  for (int g = 0; g < GQ; g++) {
    float v = ls[g];
#pragma unroll
    for (int off = 1; off < 64; off <<= 1) v += __shfl_xor(v, off, 64);
    ls[g] = v;
  }
  if (lane == 0) {
#pragma unroll
    for (int g = 0; g < GQ; g++) redl[wave][g] = ls[g];
  }
  int trow = t0 - chunk * 512;
#pragma unroll
  for (int c = 0; c < 4; c++) *(float4*)&p_s[trow + c][0] = prc[c];
  __syncthreads();   // p_s / redl complete

  // ---- phase B: PV; V-blocks in batches of 4 (16 loads in flight) ----
  float acc0 = 0.f, acc1 = 0.f, acc2 = 0.f, acc3 = 0.f;
  int d_own = tid;   // 0..127
#pragma unroll
  for (int bt4 = 0; bt4 < 8; bt4++) {
    f4v vr[4][4];
#pragma unroll
    for (int t = 0; t < 4; t++) {
      const float* vb = vbase[bt4 * 4 + t] + d_own * BS;
      vr[t][0] = *(const f4v*)(vb);
      vr[t][1] = *(const f4v*)(vb + 4);
      vr[t][2] = *(const f4v*)(vb + 8);
      vr[t][3] = *(const f4v*)(vb + 12);
    }
#pragma unroll
    for (int t = 0; t < 4; t++) {
      const float* pp = &p_s[(bt4 * 4 + t) * 16][0];
#pragma unroll
      for (int jq = 0; jq < 4; jq++) {
#pragma unroll
        for (int j = 0; j < 4; j++) {
          float4 pj = *(const float4*)(pp + (jq * 4 + j) * GQ);
          float vv = vr[t][jq][j];
          acc0 = fmaf(pj.x, vv, acc0);
          acc1 = fmaf(pj.y, vv, acc1);
          acc2 = fmaf(pj.z, vv, acc2);
          acc3 = fmaf(pj.w, vv, acc3);
        }
      }
    }
  }

  int pid = b * NKV + kv;
  float* pw = partial + ((size_t)pid * NCHUNK + chunk) * (GQ * 130);
  pw[0 * 130 + 2 + d_own] = acc0;
  pw[1 * 130 + 2 + d_own] = acc1;
  pw[2 * 130 + 2 + d_own] = acc2;
  pw[3 * 130 + 2 + d_own] = acc3;
  if (tid == 0) {
#pragma unroll
    for (int g = 0; g < GQ; g++) {
      pw[g * 130 + 0] = mb[g];
      pw[g * 130 + 1] = redl[0][g] + redl[1][g];
    }
  }
}

// ------- w_o GEMM with fused chunk-combine (X-tile built from apart in-block) -------
// k-slice [k0, k0+64) maps to head h = k0>>7 (kv=h>>2, g=h&3), d0 = k0&127.
__global__ __launch_bounds__(128, 1) void k_gemm_o(
    const float* __restrict__ apart, const float* __restrict__ W,
    float* __restrict__ part) {
  __shared__ __align__(16) float xs[B_][KS];      // combined X tile
  __shared__ float wexp[B_][NCHUNK];
  __shared__ float lw[B_];

  int tid = threadIdx.x;
  int k0 = blockIdx.y * KS;
  int h = k0 >> 7, kv = h >> 2, g = h & 3, d0 = k0 & 127;

  // per-b flash weights (threads 0..15)
  if (tid < B_) {
    int b = tid;
    const float* pb = apart + ((size_t)(b * NKV + kv) * NCHUNK) * (GQ * 130) + g * 130;
    float M = -3e38f;
#pragma unroll
    for (int c = 0; c < NCHUNK; c++) M = fmaxf(M, pb[c * (GQ * 130)]);
    float L = 0.f;
#pragma unroll
    for (int c = 0; c < NCHUNK; c++) {
      float w = __expf(pb[c * (GQ * 130)] - M);
      wexp[b][c] = w;
      L = fmaf(pb[c * (GQ * 130) + 1], w, L);
    }
    lw[b] = L;
  }
  __syncthreads();

  // build X tile: 16 b x 64 kk, 8 items/thread
#pragma unroll
  for (int it = 0; it < 8; it++) {
    int item = it * 128 + tid;
    int b = item >> 6, kk = item & 63;
    const float* pb = apart + ((size_t)(b * NKV + kv) * NCHUNK) * (GQ * 130) + g * 130 + 2 + d0 + kk;
    float val = 0.f;
#pragma unroll
    for (int c = 0; c < NCHUNK; c++) val = fmaf(pb[c * (GQ * 130)], wexp[b][c], val);
    xs[b][kk] = val / lw[b];
  }
  __syncthreads();

  int n4 = (blockIdx.x * 128 + tid) * 4;
  f4v acc[B_];
#pragma unroll
  for (int b = 0; b < B_; b++) acc[b] = (f4v){0.f, 0.f, 0.f, 0.f};
  const float* wp = W + (size_t)k0 * HIDDEN + n4;
#pragma unroll
  for (int batch = 0; batch < KS / 16; batch++) {
    f4v w[16];
#pragma unroll
    for (int i = 0; i < 16; i++)
      w[i] = *(const f4v*)&wp[(size_t)(batch * 16 + i) * HIDDEN];
#pragma unroll
    for (int i = 0; i < 16; i++) {
      int kk = batch * 16 + i;
#pragma unroll
      for (int b = 0; b < B_; b++) {
        float x = xs[b][kk];
        acc[b][0] = fmaf(x, w[i][0], acc[b][0]);
        acc[b][1] = fmaf(x, w[i][1], acc[b][1]);
        acc[b][2] = fmaf(x, w[i][2], acc[b][2]);
        acc[b][3] = fmaf(x, w[i][3], acc[b][3]);
      }
    }
  }
  float* pp = part + (size_t)blockIdx.y * B_ * HIDDEN + n4;
#pragma unroll
  for (int b = 0; b < B_; b++) *(f4v*)&pp[(size_t)b * HIDDEN] = acc[b];
}

// ---------------- reduce w_o partials -> out ----------------
__global__ __launch_bounds__(256) void k_reduce_out(
    const float* __restrict__ part, float* __restrict__ out) {
  int idx = blockIdx.x * 256 + threadIdx.x;
  int b = idx >> 12, n = idx & 4095;
  float s = 0.f;
#pragma unroll 8
  for (int ky = 0; ky < NSPLIT; ky++)
    s += part[((size_t)ky * B_ + b) * HIDDEN + n];
  out[idx] = s;
}

extern "C" void kernel_launch(void* const* d_in, const int* in_sizes, int n_in,
                              void* d_out, int out_size, void* d_ws, size_t ws_size,
                              hipStream_t stream) {
  const int*   positions = (const int*)d_in[0];
  const float* hs        = (const float*)d_in[1];
  const float* kc        = (const float*)d_in[2];
  const float* vc        = (const float*)d_in[3];
  const int*   bt        = (const int*)d_in[4];
  const float* w_qkv     = (const float*)d_in[6];
  const float* w_o       = (const float*)d_in[7];
  float* out = (float*)d_out;

  float* ws    = (float*)d_ws;
  float* ctab  = ws;                    // 262400
  float* stab  = ctab + 262400;         // 262400
  float* pk    = stab + 262400;         // 262144
  float* pv    = pk + 262144;           // 262144
  float* qbuf  = pv + 262144;           // 65536
  float* apart = qbuf + 65536;          // 128*8*4*130 = 532480
  float* gpart = apart + 532480;        // 64*16*6144 = 6291456

  k_gemm_qkv<<<dim3(QKV_COLS / 512, NSPLIT), 128, 0, stream>>>(
      hs, w_qkv, gpart, ctab, stab, pk, pv);
  k_qkv_finish<<<(B_ * 3584) / 256, 256, 0, stream>>>(gpart, positions, ctab, stab, qbuf, pk, pv);
  k_attn<<<dim3(B_ * NKV, NCHUNK), 128, 0, stream>>>(kc, vc, bt, qbuf, pk, pv, ctab, stab, apart);
  k_gemm_o<<<dim3(HIDDEN / 512, NSPLIT), 128, 0, stream>>>(apart, w_o, gpart);
  k_reduce_out<<<(B_ * HIDDEN) / 256, 256, 0, stream>>>(gpart, out);
}